// Round 1
// baseline (1196.903 us; speedup 1.0000x reference)
//
#include <hip/hip_runtime.h>
#include <cstdint>

#define Tn 200
#define En 512
#define NWG 16

// ---- embed gather for batch row 63 only ----
__global__ __launch_bounds__(128) void embed_k(const int* __restrict__ ids,
                                               const float* __restrict__ tab,
                                               float* __restrict__ x0) {
  const int t = blockIdx.x;
  const int e = threadIdx.x;
  const long id = ids[63 * Tn + t];
  const float4* src = (const float4*)(tab + (size_t)id * En);
  ((float4*)(x0 + (size_t)t * En))[e] = src[e];
}

// out[t][g] = (relu?)( A[t][:512] . W[g][:512] + bp1[g] + bp2?[g] )
// grid: (G/256, 25), block 256. A rows are 512 wide for every use here.
__global__ __launch_bounds__(256) void gemm_rows(const float* __restrict__ A,
                                                 const float* __restrict__ W,
                                                 const float* __restrict__ bp1,
                                                 const float* __restrict__ bp2,
                                                 float* __restrict__ out,
                                                 int G, int relu) {
  __shared__ float xl[8 * 512];
  const int gr = blockIdx.x * 256 + threadIdx.x;
  const int t0 = blockIdx.y * 8;
  for (int i = threadIdx.x; i < 8 * 512; i += 256) xl[i] = A[(size_t)t0 * 512 + i];
  __syncthreads();
  const float b = bp1[gr] + (bp2 ? bp2[gr] : 0.f);
  float acc[8];
#pragma unroll
  for (int tt = 0; tt < 8; tt++) acc[tt] = b;
  const float4* wr = (const float4*)(W + (size_t)gr * 512);
  for (int k4 = 0; k4 < 128; k4++) {
    const float4 w = wr[k4];
#pragma unroll
    for (int tt = 0; tt < 8; tt++) {
      const float4 xv = *(const float4*)&xl[tt * 512 + k4 * 4];
      acc[tt] = fmaf(w.x, xv.x, fmaf(w.y, xv.y, fmaf(w.z, xv.z, fmaf(w.w, xv.w, acc[tt]))));
    }
  }
#pragma unroll
  for (int tt = 0; tt < 8; tt++) {
    float v = acc[tt];
    if (relu) v = fmaxf(v, 0.f);
    out[(size_t)(t0 + tt) * G + gr] = v;
  }
}

// ---- bidirectional LSTM recurrence for one layer ----
// 16 WGs x 512 threads. WG g owns h indices [16g,16g+16) for BOTH directions.
// whh slice (64 rows fwd + 64 rows bwd) lives in registers (32+32 VGPR/thread).
// Cross-WG h exchange through hcat (device-scope atomics) + stamped flag lines.
__global__ __launch_bounds__(512) void rec_k(const float* __restrict__ xp,   // [T][2048] fwd|bwd
                                             float* __restrict__ hcat,       // [T][512] fwd|bwd cols
                                             unsigned* __restrict__ flags,   // NWG * 32 (128B apart)
                                             const float* __restrict__ whhF,
                                             const float* __restrict__ whhB,
                                             int guard) {
  __shared__ float hFs[288], hBs[288], gF[64], gB[64];
  __shared__ float pad[20480];  // 80KB pad: forces 1 WG/CU so all 16 WGs get their own CU
  const int tid = threadIdx.x;
  const int g = blockIdx.x;
  if (guard) pad[guard] = 0.f;  // guard==0 at runtime; keeps pad allocated
  const int row = tid >> 3, kc = tid & 7;   // 64 rows x 8 k-chunks
  const int gt = row >> 4, hj = row & 15;   // gate type, h index within slice
  const int gr = gt * 256 + g * 16 + hj;    // global gate row (i|f|g|o blocks of 256)

  float wF[32], wB[32];
  {
    const float* pF = whhF + (size_t)gr * 256 + kc * 32;
    const float* pB = whhB + (size_t)gr * 256 + kc * 32;
#pragma unroll
    for (int i = 0; i < 32; i++) { wF[i] = pF[i]; wB[i] = pB[i]; }
  }
  for (int i = tid; i < 288; i += 512) { hFs[i] = 0.f; hBs[i] = 0.f; }
  float c_state = 0.f;  // persistent in threads tid<32 (one h element each)
  float xf = 0.f, xb = 0.f;
  if (kc == 0) {
    xf = xp[gr];
    xb = xp[(size_t)(Tn - 1) * 2048 + 1024 + gr];
  }
  __syncthreads();

  for (int t = 0; t < Tn; ++t) {
    // gate matvec from register weights, h staged in LDS (swizzled stride 36 to spread banks)
    float aF = 0.f, aB = 0.f;
    const float* hF = &hFs[kc * 36];
    const float* hB = &hBs[kc * 36];
#pragma unroll
    for (int i = 0; i < 32; i++) {
      aF = fmaf(wF[i], hF[i], aF);
      aB = fmaf(wB[i], hB[i], aB);
    }
#pragma unroll
    for (int off = 1; off < 8; off <<= 1) {
      aF += __shfl_xor(aF, off);
      aB += __shfl_xor(aB, off);
    }
    if (kc == 0) { gF[row] = aF + xf; gB[row] = aB + xb; }
    __syncthreads();

    if (tid < 32) {  // tid<16: fwd h-slice, tid 16..31: bwd h-slice
      const int j = tid & 15;
      const float* gl = (tid < 16) ? gF : gB;
      float iv = gl[j], fv = gl[16 + j], gv = gl[32 + j], ov = gl[48 + j];
      iv = 1.f / (1.f + __expf(-iv));
      fv = 1.f / (1.f + __expf(-fv));
      gv = 1.f - 2.f / (1.f + __expf(2.f * gv));   // tanh
      ov = 1.f / (1.f + __expf(-ov));
      c_state = fv * c_state + iv * gv;
      const float th = 1.f - 2.f / (1.f + __expf(2.f * c_state));
      const float hv = ov * th;
      const int rowt = (tid < 16) ? t : (Tn - 1 - t);   // bwd writes reversed time
      const int col = ((tid < 16) ? 0 : 256) + g * 16 + j;
      __hip_atomic_store(&hcat[(size_t)rowt * 512 + col], hv, __ATOMIC_RELAXED,
                         __HIP_MEMORY_SCOPE_AGENT);
    }
    __syncthreads();  // drains vmcnt for all waves before flag post
    if (tid == 0) {
      __threadfence();
      __hip_atomic_store(&flags[g * 32], (unsigned)(t + 1), __ATOMIC_RELEASE,
                         __HIP_MEMORY_SCOPE_AGENT);
    }
    if (t + 1 < Tn) {
      // prefetch next step's xproj while flags propagate
      if (kc == 0) {
        xf = xp[(size_t)(t + 1) * 2048 + gr];
        xb = xp[(size_t)(Tn - 2 - t) * 2048 + 1024 + gr];
      }
      if (tid < 64) {  // wave 0 polls all 16 flags (separate 128B lines)
        const bool need = (tid < NWG);
        unsigned v = 0;
        int itc = 0;
        do {
          v = need ? __hip_atomic_load(&flags[tid * 32], __ATOMIC_ACQUIRE,
                                       __HIP_MEMORY_SCOPE_AGENT)
                   : 0u;
        } while (__ballot(need && (v < (unsigned)(t + 1))) != 0ull && ++itc < 65536);
      }
      __syncthreads();
      // reload full h(t) for both directions (512 values, one per thread)
      float hv;
      if (tid < 256)
        hv = __hip_atomic_load(&hcat[(size_t)t * 512 + tid], __ATOMIC_RELAXED,
                               __HIP_MEMORY_SCOPE_AGENT);
      else
        hv = __hip_atomic_load(&hcat[(size_t)(Tn - 1 - t) * 512 + tid], __ATOMIC_RELAXED,
                               __HIP_MEMORY_SCOPE_AGENT);
      const int k = tid & 255;
      float* dst = (tid < 256) ? hFs : hBs;
      dst[(k >> 5) * 36 + (k & 31)] = hv;
      __syncthreads();
    }
  }
}

// ---- final 1024->7 matmul + softmax per timestep ----
__global__ __launch_bounds__(64) void mlp2_k(const float* __restrict__ h1,
                                             const float* __restrict__ w2,
                                             const float* __restrict__ b2,
                                             float* __restrict__ out) {
  __shared__ float hrow[1024];
  __shared__ float lg[8];
  const int t = blockIdx.x, tid = threadIdx.x;
  for (int i = tid; i < 1024; i += 64) hrow[i] = h1[(size_t)t * 1024 + i];
  __syncthreads();
  const int o = tid >> 3, kc = tid & 7;
  float acc = 0.f;
  if (o < 7) {
    const float* w = w2 + (size_t)o * 1024 + kc * 128;
    const float* h = &hrow[kc * 128];
    for (int j = 0; j < 128; j++) acc = fmaf(w[j], h[j], acc);
  }
#pragma unroll
  for (int off = 1; off < 8; off <<= 1) acc += __shfl_xor(acc, off);
  if (o < 7 && kc == 0) lg[o] = acc + b2[o];
  __syncthreads();
  if (tid == 0) {
    float mx = -1e30f;
#pragma unroll
    for (int i = 0; i < 7; i++) mx = fmaxf(mx, lg[i]);
    float e[7];
    float s = 0.f;
#pragma unroll
    for (int i = 0; i < 7; i++) { e[i] = __expf(lg[i] - mx); s += e[i]; }
    const float inv = 1.f / s;
#pragma unroll
    for (int i = 0; i < 7; i++) out[t * 7 + i] = e[i] * inv;
  }
}

extern "C" void kernel_launch(void* const* d_in, const int* in_sizes, int n_in,
                              void* d_out, int out_size, void* d_ws, size_t ws_size,
                              hipStream_t stream) {
  const int* ids = (const int*)d_in[0];
  const float* tab = (const float*)d_in[1];
  const float* wih = (const float*)d_in[2];   // (2,2,1024,512)
  const float* whh = (const float*)d_in[3];   // (2,2,1024,256)
  const float* bih = (const float*)d_in[4];   // (2,2,1024)
  const float* bhh = (const float*)d_in[5];
  const float* w1 = (const float*)d_in[6];    // (1024,512)
  const float* b1 = (const float*)d_in[7];
  const float* w2 = (const float*)d_in[8];    // (7,1024)
  const float* b2 = (const float*)d_in[9];
  float* out = (float*)d_out;                 // (200,7) f32
  float* ws = (float*)d_ws;

  float* x0 = ws;                     // 200*512
  float* xp = ws + 102400;            // 200*2048 (reused both layers)
  float* h0 = ws + 512000;            // 200*512
  float* h1 = ws + 614400;            // 200*512
  float* hm = ws + 716800;            // 200*1024
  unsigned* flags = (unsigned*)(ws + 921600);  // 2 * NWG * 32 u32

  hipMemsetAsync(flags, 0, 2 * NWG * 32 * sizeof(unsigned), stream);
  embed_k<<<Tn, 128, 0, stream>>>(ids, tab, x0);
  // layer 0: xproj for both dirs (wih rows 0..2047 contiguous), then recurrence
  gemm_rows<<<dim3(8, 25), 256, 0, stream>>>(x0, wih, bih, bhh, xp, 2048, 0);
  rec_k<<<NWG, 512, 0, stream>>>(xp, h0, flags, whh, whh + 262144, 0);
  // layer 1
  gemm_rows<<<dim3(8, 25), 256, 0, stream>>>(h0, wih + 1048576, bih + 2048, bhh + 2048, xp, 2048, 0);
  rec_k<<<NWG, 512, 0, stream>>>(xp, h1, flags + NWG * 32, whh + 524288, whh + 786432, 0);
  // MLP: h = relu(hcat1 @ w1^T + b1); logits/softmax
  gemm_rows<<<dim3(4, 25), 256, 0, stream>>>(h1, w1, b1, nullptr, hm, 1024, 1);
  mlp2_k<<<Tn, 64, 0, stream>>>(hm, w2, b2, out);
}